// Round 1
// baseline (626.209 us; speedup 1.0000x reference)
//
#include <hip/hip_runtime.h>

// 2-layer LSTM (H=12), B=8192, T=1024 + 64 free-running steps.
// R7: register-closed recurrence — ZERO LDS, ZERO barriers.
// One wave = 16 batch elements, full chain. Per cell: 3x mfma_f32_16x16x32_f16.
//
// Row order:  R = 4*v + q  (v = output unit 0..11, q = gate i/f/g/o).
//   Chunk c covers rows 16c..16c+15; D row 4g+reg -> unit v=4c+g, gate q=reg.
//   So lane (g,n) computes acts for units {g, 4+g, 8+g} at column n.
// K order:    k = 8*(u mod 4) + (u div 4); pads at j=3,7 of each group.
//   B slot k=8g+j (j<3) = h_{4j+g}[n] -> exactly this lane's own act outputs.
//   => D->B handoff is lane-local: the whole recurrence stays in registers.
// Cell1 B reuses the {h1,h2} pack; h2 slots multiply EXPLICIT ZERO A1 entries.
// x applied in f32 via fmaf(wi1,x,D) (same precision path as R6).
// y = w_lin . h2: 3 fmaf partial + shfl_xor(16) + shfl_xor(32); not on the
// recurrence critical path.
//
// Fragment maps (gfx950, HW-verified):
//   A[m=lane&15][k=8*(lane>>4)+j], B[k=8*(lane>>4)+j][n=lane&15],
//   D[row=4*(lane>>4)+reg][col=lane&15].

typedef _Float16 v8h  __attribute__((ext_vector_type(8)));
typedef float    v4f  __attribute__((ext_vector_type(4)));

constexpr int H   = 12;
constexpr int T   = 1024;
constexpr int FUT = 64;
constexpr int TT  = T + FUT;   // 1088
constexpr int B   = 8192;

static __device__ __forceinline__ float fexp2(float x){ return __builtin_amdgcn_exp2f(x); }
static __device__ __forceinline__ float frcp (float x){ return __builtin_amdgcn_rcpf(x); }

__global__ __launch_bounds__(64) void lstm_reg_kernel(
    const float* __restrict__ input,
    const float* __restrict__ w_ih1, const float* __restrict__ w_hh1,
    const float* __restrict__ b_ih1, const float* __restrict__ b_hh1,
    const float* __restrict__ w_ih2, const float* __restrict__ w_hh2,
    const float* __restrict__ b_ih2, const float* __restrict__ b_hh2,
    const float* __restrict__ w_lin, const float* __restrict__ b_lin,
    float* __restrict__ out)
{
  const int lane = threadIdx.x & 63;
  const int g    = lane >> 4;       // lane group: unit residue (u mod 4)
  const int n    = lane & 15;       // element column
  const int e0   = blockIdx.x * 16;

  const float L2E = 1.4426950408889634f;
  const float sc[4] = { -L2E, -L2E, 2.0f * L2E, -L2E };  // i,f,g,o prescale
  const float TWO_L2E = 2.885390081777927f;

  // ---------------- A fragments: 3 chunks per cell, prescaled ------------
  // A-row m = lane&15 = n. Chunk c row m -> v = 4c + (m>>2), q = m&3,
  // storage row = q*12 + v. k slot j<3 -> u = 4j+g; j+4 (4..6) -> same u (h2).
  v8h A1[3], A2[3];
  {
    const int q = n & 3;
    #pragma unroll
    for (int c = 0; c < 3; ++c) {
      const int v   = 4 * c + (n >> 2);
      const int row = q * 12 + v;
      v8h a1 = {0,0,0,0,0,0,0,0}, a2 = {0,0,0,0,0,0,0,0};
      #pragma unroll
      for (int j = 0; j < 3; ++j) {
        const int u = 4 * j + g;
        a1[j]     = (_Float16)(sc[q] * w_hh1[row * 12 + u]);   // cell1: h1 cols
        a2[j]     = (_Float16)(sc[q] * w_ih2[row * 12 + u]);   // cell2: h1 cols
        a2[j + 4] = (_Float16)(sc[q] * w_hh2[row * 12 + u]);   // cell2: h2 cols
      }
      // a1 slots 3..7 stay 0: h2/pad columns contribute nothing to cell1.
      A1[c] = a1; A2[c] = a2;
    }
  }

  // ---------------- C bias fragments + x weights + y weights -------------
  // D rows 4g+reg of chunk c -> unit v = 4c+g, gate q = reg.
  v4f  C1[3], C2[3];
  float wi1[3][4], wl[3];
  #pragma unroll
  for (int c = 0; c < 3; ++c) {
    const int v = 4 * c + g;
    #pragma unroll
    for (int r = 0; r < 4; ++r) {
      C1[c][r]  = sc[r] * (b_ih1[r * 12 + v] + b_hh1[r * 12 + v]);
      C2[c][r]  = sc[r] * (b_ih2[r * 12 + v] + b_hh2[r * 12 + v]);
      wi1[c][r] = sc[r] * w_ih1[r * 12 + v];
    }
    wl[c] = w_lin[v];
  }
  const float blin = b_lin[0];

  // ---------------- state (all registers) --------------------------------
  float c1s[3] = {0,0,0}, c2s[3] = {0,0,0};
  float h1f[3] = {0,0,0}, h2f[3] = {0,0,0};

  const float* xrow   = input + (size_t)(e0 + n) * T;
  float*       yrow   = out   + (size_t)(e0 + n) * TT;
  const bool   ystore = (g == 3);
  const float  xl     = xrow[T - 1];

  auto act = [&](float g0, float g1, float g2v, float g3, float& cs) -> float {
    const float Ai = fexp2(g0);          // e^{-i}
    const float Af = fexp2(g1);          // e^{-f}
    const float Eg = fexp2(g2v);         // e^{2g}
    const float Ao = fexp2(g3);          // e^{-o}
    const float pf = 1.0f + Af;
    const float P  = (1.0f + Ai) * (1.0f + Eg);
    cs = fmaf(cs, P, (Eg - 1.0f) * pf) * frcp(P * pf);   // sig(f)c + sig(i)tanh(g)
    const float Ec = fexp2(TWO_L2E * cs);                // e^{2c}
    return (Ec - 1.0f) * frcp((1.0f + Ao) * (1.0f + Ec)); // sig(o)tanh(c)
  };

  auto step = [&](float x) -> float {
    // ---- cell 1: B = {h1(t-1), 0, h2(t-1), 0}; h2 slots hit A1 zeros ----
    v8h Bv;
    Bv[0] = (_Float16)h1f[0]; Bv[1] = (_Float16)h1f[1]; Bv[2] = (_Float16)h1f[2];
    Bv[3] = (_Float16)0.0f;
    Bv[4] = (_Float16)h2f[0]; Bv[5] = (_Float16)h2f[1]; Bv[6] = (_Float16)h2f[2];
    Bv[7] = (_Float16)0.0f;

    v4f D0 = __builtin_amdgcn_mfma_f32_16x16x32_f16(A1[0], Bv, C1[0], 0, 0, 0);
    v4f D1 = __builtin_amdgcn_mfma_f32_16x16x32_f16(A1[1], Bv, C1[1], 0, 0, 0);
    v4f D2 = __builtin_amdgcn_mfma_f32_16x16x32_f16(A1[2], Bv, C1[2], 0, 0, 0);

    h1f[0] = act(fmaf(wi1[0][0], x, D0[0]), fmaf(wi1[0][1], x, D0[1]),
                 fmaf(wi1[0][2], x, D0[2]), fmaf(wi1[0][3], x, D0[3]), c1s[0]);
    h1f[1] = act(fmaf(wi1[1][0], x, D1[0]), fmaf(wi1[1][1], x, D1[1]),
                 fmaf(wi1[1][2], x, D1[2]), fmaf(wi1[1][3], x, D1[3]), c1s[1]);
    h1f[2] = act(fmaf(wi1[2][0], x, D2[0]), fmaf(wi1[2][1], x, D2[1]),
                 fmaf(wi1[2][2], x, D2[2]), fmaf(wi1[2][3], x, D2[3]), c1s[2]);

    // ---- cell 2: B = {h1(t), 0, h2(t-1), 0} — update h1 halves only -----
    v8h B2 = Bv;
    B2[0] = (_Float16)h1f[0]; B2[1] = (_Float16)h1f[1]; B2[2] = (_Float16)h1f[2];

    v4f E0 = __builtin_amdgcn_mfma_f32_16x16x32_f16(A2[0], B2, C2[0], 0, 0, 0);
    v4f E1 = __builtin_amdgcn_mfma_f32_16x16x32_f16(A2[1], B2, C2[1], 0, 0, 0);
    v4f E2 = __builtin_amdgcn_mfma_f32_16x16x32_f16(A2[2], B2, C2[2], 0, 0, 0);

    h2f[0] = act(E0[0], E0[1], E0[2], E0[3], c2s[0]);
    h2f[1] = act(E1[0], E1[1], E1[2], E1[3], c2s[1]);
    h2f[2] = act(E2[0], E2[1], E2[2], E2[3], c2s[2]);

    // ---- y(t) = w_lin . h2(t) + b: off the recurrence critical path -----
    float yp = h2f[0] * wl[0];
    yp = fmaf(h2f[1], wl[1], yp);
    yp = fmaf(h2f[2], wl[2], yp);
    yp += __shfl_xor(yp, 16);
    yp += __shfl_xor(yp, 32);
    return yp + blin;
  };

  // Software-pipelined x loads: next float4 issued before the 4 substeps.
  float4 xv = *reinterpret_cast<const float4*>(xrow);
  for (int tb = 0; tb < TT; tb += 4) {
    float4 xnext;
    if (tb + 4 < T) xnext = *reinterpret_cast<const float4*>(xrow + tb + 4);
    else            xnext = make_float4(xl, xl, xl, xl);

    float4 yb;
    yb.x = step(xv.x);
    yb.y = step(xv.y);
    yb.z = step(xv.z);
    yb.w = step(xv.w);
    if (ystore) *reinterpret_cast<float4*>(yrow + tb) = yb;
    xv = xnext;
  }
}

extern "C" void kernel_launch(void* const* d_in, const int* in_sizes, int n_in,
                              void* d_out, int out_size, void* d_ws, size_t ws_size,
                              hipStream_t stream) {
  const float* input = (const float*)d_in[0];
  const float* w_ih1 = (const float*)d_in[2];
  const float* w_hh1 = (const float*)d_in[3];
  const float* b_ih1 = (const float*)d_in[4];
  const float* b_hh1 = (const float*)d_in[5];
  const float* w_ih2 = (const float*)d_in[6];
  const float* w_hh2 = (const float*)d_in[7];
  const float* b_ih2 = (const float*)d_in[8];
  const float* b_hh2 = (const float*)d_in[9];
  const float* w_lin = (const float*)d_in[10];
  const float* b_lin = (const float*)d_in[11];
  float* out = (float*)d_out;

  dim3 grid(B / 16);   // 512 single-wave chains; 2 per CU
  dim3 block(64);
  hipLaunchKernelGGL(lstm_reg_kernel, grid, block, 0, stream,
                     input, w_ih1, w_hh1, b_ih1, b_hh1,
                     w_ih2, w_hh2, b_ih2, b_hh2, w_lin, b_lin, out);
}